// Round 5
// baseline (719.480 us; speedup 1.0000x reference)
//
#include <hip/hip_runtime.h>
#include <math.h>

#define N_ROWS 32768
#define D 256
#define K 1024
#define DEPTH 3
#define MARGIN 0.05f

typedef __bf16 bf16x8 __attribute__((ext_vector_type(8)));
typedef float f32x4 __attribute__((ext_vector_type(4)));

// ---- ws layout (bytes) ----
// 0        idxAll[3][32768] int        -> 393216
// 393216   counts[3][1024] int         -> 405504
// 405504   flagcnt[3] int (pad to 405520)
// 405520   flaglist[32768] int         -> 536592
// 536592   ssepart[3][2048] double     -> 585744
// 585744   e2f[3][1024] float          -> 598032 (pad to 598080)
// 598080   cbp bf16 [3][1024][512]     -> 3743808
// 3743808  rp  bf16 [32768][512]       -> 37298240

__device__ __forceinline__ void gload_lds16(const void* g, void* l) {
    __builtin_amdgcn_global_load_lds(
        (const __attribute__((address_space(1))) void*)g,
        (__attribute__((address_space(3))) void*)l, 16, 0, 0);
}

__device__ __forceinline__ unsigned short f2bf(float f) {
    unsigned u = __float_as_uint(f);
    return (unsigned short)((u + 0x7fffu + ((u >> 16) & 1u)) >> 16);
}

// one wave per codebook row
__global__ __launch_bounds__(256) void e2_kernel(
    const float* __restrict__ cbs, float* __restrict__ e2f)
{
    int t = blockIdx.x * 256 + threadIdx.x;    // 768 blocks -> 3072 rows
    int row = t >> 6;
    int lane = t & 63;
    float4 v = *(const float4*)(cbs + (size_t)row * D + lane * 4);
    double s = (double)v.x * v.x + (double)v.y * v.y
             + (double)v.z * v.z + (double)v.w * v.w;
    for (int o = 32; o > 0; o >>= 1) s += __shfl_down(s, o, 64);
    if (lane == 0) e2f[row] = (float)s;
}

// Pack fp32 rows into [hi(256)|lo(256)] bf16 rows (stage-0 z pack and codebooks).
__global__ __launch_bounds__(256) void pack_kernel(
    const float* __restrict__ src, unsigned short* __restrict__ dst)
{
    int t = blockIdx.x * 256 + threadIdx.x;
    int row = t >> 5;
    int k8 = (t & 31) * 8;
    size_t off = (size_t)row * D + k8;
    float4 v0 = *(const float4*)(src + off);
    float4 v1 = *(const float4*)(src + off + 4);
    float v[8] = {v0.x, v0.y, v0.z, v0.w, v1.x, v1.y, v1.z, v1.w};
    typedef __attribute__((ext_vector_type(8))) unsigned short u16x8;
    u16x8 hv, lv;
    #pragma unroll
    for (int j = 0; j < 8; ++j) {
        ushort h = f2bf(v[j]);
        hv[j] = h;
        float hf = __uint_as_float(((unsigned)h) << 16);
        lv[j] = f2bf(v[j] - hf);
    }
    *(u16x8*)(dst + (size_t)row * 512 + k8) = hv;
    *(u16x8*)(dst + (size_t)row * 512 + 256 + k8) = lv;
}

// 64 rows resident in swizzled LDS; A-fragments loaded DIRECTLY global->VGPR
// (cbp is L2-resident); zero barriers in the main loop; A double-buffered
// one phase ahead. Writes final argmin + near-tie flags.
__global__ __launch_bounds__(256, 2) void mfma_argmin_kernel(
    const unsigned short* __restrict__ cbp,   // [1024][512] packed bf16
    const unsigned short* __restrict__ rp,    // [32768][512] packed bf16
    const float* __restrict__ e2f,            // [1024]
    int* __restrict__ idxOut, int* __restrict__ flagcnt, int* __restrict__ flaglist)
{
    __shared__ __align__(16) __bf16 Bsm[64 * 512];   // 64 KB resident rows
    __shared__ float4 mb[128];                        // merge scratch (2 KB)

    const int tid = threadIdx.x;
    const int lane = tid & 63;
    const int w = tid >> 6;
    const int wm = w >> 1, wn = w & 1;     // wm: code half, wn: row half
    const int hi = lane >> 4;              // 0..3
    const int lo16 = lane & 15;
    const int row0 = blockIdx.x * 64;

    // ---- stage resident B rows once (swizzled: linear dest, inverse-swz source) ----
    #pragma unroll
    for (int rr = 0; rr < 16; ++rr) {
        int q = rr * 256 + tid;            // 16B-chunk id, 4096 total
        int row = q >> 6;
        int lc = (q & 63) ^ (row & 7);
        gload_lds16(rp + (size_t)(row0 + row) * 512 + lc * 8, (char*)Bsm + q * 16);
    }

    // K=768 three-term split: A windows hi,lo,hi ; B windows hi,hi,lo (elems)
    constexpr int aO[12] = {0,64,128,192, 256,320,384,448, 0,64,128,192};
    constexpr int bO[12] = {0,64,128,192, 0,64,128,192, 256,320,384,448};

    // per-lane A base: code = wm*64 + lo16 (+m*16 +cc*128), elems hi*8 within window
    const unsigned short* aBase = cbp + (size_t)(wm * 64 + lo16) * 512 + hi * 8;

    float d1[2], d2[2];
    int   i1[2], i2[2];
    #pragma unroll
    for (int n = 0; n < 2; ++n) {
        d1[n] = 3.4e38f; d2[n] = 3.4e38f;
        i1[n] = 0x7fffffff; i2[n] = 0x7fffffff;
    }

    // prologue: load (cc=0, s=0) A-frags into parity buffer 0
    bf16x8 af[2][4][2];
    #pragma unroll
    for (int m = 0; m < 4; ++m)
        #pragma unroll
        for (int kk = 0; kk < 2; ++kk)
            af[0][m][kk] = *(const bf16x8*)(aBase + m * 8192 + aO[0] + kk * 32);

    __syncthreads();                       // B resident; only barrier before merge

    for (int cc = 0; cc < 8; ++cc) {
        const unsigned short* aCc = aBase + cc * 65536;    // 128 codes * 512 elems
        f32x4 acc[4][2];
        #pragma unroll
        for (int m = 0; m < 4; ++m)
            #pragma unroll
            for (int n = 0; n < 2; ++n)
                acc[m][n] = (f32x4){0.f, 0.f, 0.f, 0.f};

        #pragma unroll
        for (int s = 0; s < 12; ++s) {
            const int p = s & 1;
            // prefetch next phase (next window, or next cc's first window)
            const unsigned short* aN =
                (s < 11) ? (aCc + aO[s + 1]) : (aCc + 65536 + aO[0]);
            #pragma unroll
            for (int m = 0; m < 4; ++m)
                #pragma unroll
                for (int kk = 0; kk < 2; ++kk)
                    af[p ^ 1][m][kk] = *(const bf16x8*)(aN + m * 8192 + kk * 32);

            #pragma unroll
            for (int kk = 0; kk < 2; ++kk) {
                bf16x8 bfv[2];
                #pragma unroll
                for (int n = 0; n < 2; ++n) {
                    int rw = wn * 32 + n * 16 + lo16;
                    int lb = rw * 1024 + bO[s] * 2 + kk * 64 + hi * 16;
                    bfv[n] = *(const bf16x8*)((const char*)Bsm + (lb ^ ((rw & 7) << 4)));
                }
                #pragma unroll
                for (int m = 0; m < 4; ++m)
                    #pragma unroll
                    for (int n = 0; n < 2; ++n)
                        acc[m][n] = __builtin_amdgcn_mfma_f32_16x16x32_bf16(
                            af[p][m][kk], bfv[n], acc[m][n], 0, 0, 0);
            }
        }

        // epilogue: dist = e2 - 2*dot ; update per-lane top-2 (codes ascending)
        const int cb0 = cc * 128;
        float e2a[4][4];
        #pragma unroll
        for (int m = 0; m < 4; ++m) {
            float4 t = *(const float4*)(e2f + cb0 + wm * 64 + m * 16 + hi * 4);
            e2a[m][0] = t.x; e2a[m][1] = t.y; e2a[m][2] = t.z; e2a[m][3] = t.w;
        }
        #pragma unroll
        for (int n = 0; n < 2; ++n)
            #pragma unroll
            for (int m = 0; m < 4; ++m)
                #pragma unroll
                for (int r = 0; r < 4; ++r) {
                    float dv = e2a[m][r] - 2.0f * acc[m][n][r];
                    int c = cb0 + wm * 64 + m * 16 + hi * 4 + r;
                    if (dv < d1[n])      { d2[n] = d1[n]; i2[n] = i1[n]; d1[n] = dv; i1[n] = c; }
                    else if (dv < d2[n]) { d2[n] = dv; i2[n] = c; }
                }
    }

    // butterfly merge across the 4 hi-groups (same rows, different codes)
    #pragma unroll
    for (int n = 0; n < 2; ++n) {
        #pragma unroll
        for (int mk = 0; mk < 2; ++mk) {
            int mask = mk ? 32 : 16;
            float od1 = __shfl_xor(d1[n], mask, 64);
            float od2 = __shfl_xor(d2[n], mask, 64);
            int   oi1 = __shfl_xor(i1[n], mask, 64);
            int   oi2 = __shfl_xor(i2[n], mask, 64);
            if (od1 < d1[n] || (od1 == d1[n] && oi1 < i1[n])) { d2[n] = d1[n]; i2[n] = i1[n]; d1[n] = od1; i1[n] = oi1; }
            else if (od1 < d2[n] || (od1 == d2[n] && oi1 < i2[n])) { d2[n] = od1; i2[n] = oi1; }
            if (od2 < d1[n] || (od2 == d1[n] && oi2 < i1[n])) { d2[n] = d1[n]; i2[n] = i1[n]; d1[n] = od2; i1[n] = oi2; }
            else if (od2 < d2[n] || (od2 == d2[n] && oi2 < i2[n])) { d2[n] = od2; i2[n] = oi2; }
        }
    }

    // cross-wm merge via LDS
    __syncthreads();
    if (lane < 16) {
        #pragma unroll
        for (int n = 0; n < 2; ++n)
            mb[wm * 64 + wn * 32 + n * 16 + lo16] =
                make_float4(d1[n], d2[n], __int_as_float(i1[n]), __int_as_float(i2[n]));
    }
    __syncthreads();
    if (tid < 64) {
        float4 p = mb[tid];
        float4 q = mb[64 + tid];
        float fd1 = p.x, fd2 = p.y;
        int   fi1 = __float_as_int(p.z), fi2 = __float_as_int(p.w);
        float qd1 = q.x, qd2 = q.y;
        int   qi1 = __float_as_int(q.z), qi2 = __float_as_int(q.w);
        if (qd1 < fd1 || (qd1 == fd1 && qi1 < fi1)) { fd2 = fd1; fi2 = fi1; fd1 = qd1; fi1 = qi1; }
        else if (qd1 < fd2 || (qd1 == fd2 && qi1 < fi2)) { fd2 = qd1; fi2 = qi1; }
        if (qd2 < fd1 || (qd2 == fd1 && qi2 < fi1)) { fd2 = fd1; fi2 = fi1; fd1 = qd2; fi1 = qi2; }
        else if (qd2 < fd2 || (qd2 == fd2 && qi2 < fi2)) { fd2 = qd2; fi2 = qi2; }
        int row = row0 + tid;
        idxOut[row] = fi1;
        if (fd2 - fd1 < MARGIN) {
            int pos = atomicAdd(flagcnt, 1);
            if (pos < N_ROWS) flaglist[pos] = row;
        }
    }
}

// Exact fp64 re-rank for near-tie rows. residual = z - (useQ ? qtot : 0).
__global__ __launch_bounds__(256) void refine_kernel(
    const float* __restrict__ z, const float* __restrict__ qtot,
    const float* __restrict__ cb, int* __restrict__ idxOut,
    const int* __restrict__ flagcnt, const int* __restrict__ flaglist, int useQ)
{
    __shared__ double rres[D];
    __shared__ double bd[256];
    __shared__ int    bidx[256];
    const int tid = threadIdx.x;
    int cnt = *flagcnt;
    if (cnt > N_ROWS) cnt = N_ROWS;
    for (int f = blockIdx.x; f < cnt; f += gridDim.x) {
        int row = flaglist[f];
        __syncthreads();
        {
            float zv = z[(size_t)row * D + tid];
            float qv = useQ ? qtot[(size_t)row * D + tid] : 0.0f;
            rres[tid] = (double)(zv - qv);
        }
        __syncthreads();
        double best = 1e300; int bi = 0;
        for (int j = 0; j < 4; ++j) {
            int c = tid * 4 + j;
            const float* cp = cb + (size_t)c * D;
            double s = 0.0;
            for (int k = 0; k < D; ++k) {
                double df = rres[k] - (double)cp[k];
                s = fma(df, df, s);
            }
            if (s < best) { best = s; bi = c; }
        }
        bd[tid] = best; bidx[tid] = bi;
        __syncthreads();
        for (int off = 128; off > 0; off >>= 1) {
            if (tid < off) {
                if (bd[tid + off] < bd[tid] ||
                    (bd[tid + off] == bd[tid] && bidx[tid + off] < bidx[tid])) {
                    bd[tid] = bd[tid + off]; bidx[tid] = bidx[tid + off];
                }
            }
            __syncthreads();
        }
        if (tid == 0) idxOut[row] = bidx[0];
        __syncthreads();
    }
}

// Fused: qtot += cb[idx]; residual = z - qtot; pack residual (optional);
// SSE partial per block; counts. One pass over memory.
__global__ __launch_bounds__(256) void fused_update_kernel(
    const float* __restrict__ z, float* __restrict__ qtot,
    const float* __restrict__ cb, const int* __restrict__ idxStage,
    unsigned short* __restrict__ rpOut, int* __restrict__ counts,
    double* __restrict__ ssepart, int writeRp, int firstStage)
{
    double s = 0.0;
    const int base = blockIdx.x * 256 + threadIdx.x;
    #pragma unroll
    for (int it = 0; it < 4; ++it) {
        int t = base + it * 524288;            // quad id over N_ROWS*64
        int row = t >> 6;
        int c4  = (t & 63) << 2;
        int idx = idxStage[row];
        size_t off = (size_t)row * D + c4;
        float4 cv = *(const float4*)(cb + (size_t)idx * D + c4);
        float4 qv;
        if (firstStage) {
            qv = cv;
        } else {
            qv = *(const float4*)(qtot + off);
            qv.x += cv.x; qv.y += cv.y; qv.z += cv.z; qv.w += cv.w;
        }
        *(float4*)(qtot + off) = qv;
        float4 zv = *(const float4*)(z + off);
        float r0 = zv.x - qv.x, r1 = zv.y - qv.y;
        float r2 = zv.z - qv.z, r3 = zv.w - qv.w;
        s = fma((double)r0, (double)r0, s);
        s = fma((double)r1, (double)r1, s);
        s = fma((double)r2, (double)r2, s);
        s = fma((double)r3, (double)r3, s);
        if (writeRp) {
            float rv[4] = {r0, r1, r2, r3};
            ushort4 hv, lv;
            ushort* hp = (ushort*)&hv; ushort* lp = (ushort*)&lv;
            #pragma unroll
            for (int j = 0; j < 4; ++j) {
                ushort h = f2bf(rv[j]);
                hp[j] = h;
                float hf = __uint_as_float(((unsigned)h) << 16);
                lp[j] = f2bf(rv[j] - hf);
            }
            *(ushort4*)(rpOut + (size_t)row * 512 + c4) = hv;
            *(ushort4*)(rpOut + (size_t)row * 512 + 256 + c4) = lv;
        }
        if ((t & 63) == 0) atomicAdd(counts + idx, 1);
    }
    for (int o = 32; o > 0; o >>= 1) s += __shfl_down(s, o, 64);
    __shared__ double wsum[4];
    int lane = threadIdx.x & 63, wv = threadIdx.x >> 6;
    if (lane == 0) wsum[wv] = s;
    __syncthreads();
    if (threadIdx.x == 0)
        ssepart[blockIdx.x] = wsum[0] + wsum[1] + wsum[2] + wsum[3];
}

__global__ void compose_kernel(const int* __restrict__ idxAll, float* __restrict__ comp) {
    int n = blockIdx.x * 256 + threadIdx.x;
    if (n < N_ROWS) {
        int v = idxAll[n] + (idxAll[N_ROWS + n] << 10) + (idxAll[2 * N_ROWS + n] << 20);
        comp[n] = (float)v;
    }
}

__global__ void finalize_kernel(const int* __restrict__ counts, const double* __restrict__ ssepart,
                                float* __restrict__ loss, float* __restrict__ perps)
{
    __shared__ double red[16];
    __shared__ double lossAcc;
    const int tid = threadIdx.x;   // 1024 threads
    if (tid == 0) lossAcc = 0.0;
    __syncthreads();
    for (int d = 0; d < DEPTH; ++d) {
        double p = (double)counts[d * K + tid] / 32768.0;
        double s = p * log(p + 1e-10);
        double q = ssepart[d * 2048 + tid] + ssepart[d * 2048 + 1024 + tid];
        for (int o = 32; o > 0; o >>= 1) {
            s += __shfl_down(s, o, 64);
            q += __shfl_down(q, o, 64);
        }
        if ((tid & 63) == 0) red[tid >> 6] = s;
        __syncthreads();
        if (tid == 0) {
            double tot = 0.0;
            for (int i = 0; i < 16; ++i) tot += red[i];
            perps[d] = (float)exp(-tot);
        }
        __syncthreads();
        if ((tid & 63) == 0) red[tid >> 6] = q;
        __syncthreads();
        if (tid == 0) {
            double tq = 0.0;
            for (int i = 0; i < 16; ++i) tq += red[i];
            lossAcc += tq;
        }
        __syncthreads();
    }
    if (tid == 0)
        loss[0] = (float)(1.25 * lossAcc / 8388608.0);
}

extern "C" void kernel_launch(void* const* d_in, const int* in_sizes, int n_in,
                              void* d_out, int out_size, void* d_ws, size_t ws_size,
                              hipStream_t stream)
{
    const float* z   = (const float*)d_in[0];
    const float* cbs = (const float*)d_in[1];
    float* out = (float*)d_out;
    char*  ws  = (char*)d_ws;

    int*            idxAll   = (int*)ws;
    int*            counts   = (int*)(ws + 393216);
    int*            flagcnt  = (int*)(ws + 405504);
    int*            flaglist = (int*)(ws + 405520);
    double*         ssepart  = (double*)(ws + 536592);
    float*          e2f      = (float*)(ws + 585744);
    unsigned short* cbp      = (unsigned short*)(ws + 598080);
    unsigned short* rp       = (unsigned short*)(ws + 3743808);

    float* qtot  = out;                       // 8388608 elems
    float* loss  = out + 8388608;             // 1
    float* comp  = out + 8388609;             // 32768
    float* perps = out + 8388609 + 32768;     // 3

    hipMemsetAsync(ws + 393216, 0, 405520 - 393216, stream);  // counts + flagcnt

    e2_kernel<<<768, 256, 0, stream>>>(cbs, e2f);
    pack_kernel<<<(3072 * 32) / 256, 256, 0, stream>>>(cbs, cbp);    // codebooks
    pack_kernel<<<(N_ROWS * 32) / 256, 256, 0, stream>>>(z, rp);     // stage-0 residual = z

    for (int d = 0; d < DEPTH; ++d) {
        const float* cb = cbs + (size_t)d * K * D;
        mfma_argmin_kernel<<<512, 256, 0, stream>>>(
            cbp + (size_t)d * K * 512, rp, e2f + d * K,
            idxAll + d * N_ROWS, flagcnt + d, flaglist);
        refine_kernel<<<128, 256, 0, stream>>>(
            z, qtot, cb, idxAll + d * N_ROWS, flagcnt + d, flaglist, d > 0 ? 1 : 0);
        fused_update_kernel<<<2048, 256, 0, stream>>>(
            z, qtot, cb, idxAll + d * N_ROWS, rp, counts + d * K,
            ssepart + d * 2048, d < DEPTH - 1 ? 1 : 0, d == 0 ? 1 : 0);
    }

    compose_kernel<<<(N_ROWS + 255) / 256, 256, 0, stream>>>(idxAll, comp);
    finalize_kernel<<<1, 1024, 0, stream>>>(counts, ssepart, loss, perps);
}

// Round 6
// 530.516 us; speedup vs baseline: 1.3562x; 1.3562x over previous
//
#include <hip/hip_runtime.h>
#include <math.h>

#define N_ROWS 32768
#define D 256
#define K 1024
#define DEPTH 3
#define MARGIN 0.05f

typedef __bf16 bf16x8 __attribute__((ext_vector_type(8)));
typedef float f32x4 __attribute__((ext_vector_type(4)));

// ---- ws layout (bytes) ----
// 0        idxAll[3][32768] int        -> 393216
// 393216   counts[3][1024] int         -> 405504
// 405504   flagcnt[3] int (pad to 405520)
// 405520   flaglist[32768] int         -> 536592
// 536592   ssepart[3][2048] double     -> 585744
// 585744   e2f[3][1024] float          -> 598032 (pad to 598080)
// 598080   cbp bf16 [3][1024][512]     -> 3743808
// 3743808  rp  bf16 [32768][512]       -> 37298240

__device__ __forceinline__ void gload_lds16(const void* g, void* l) {
    __builtin_amdgcn_global_load_lds(
        (const __attribute__((address_space(1))) void*)g,
        (__attribute__((address_space(3))) void*)l, 16, 0, 0);
}

__device__ __forceinline__ unsigned short f2bf(float f) {
    unsigned u = __float_as_uint(f);
    return (unsigned short)((u + 0x7fffu + ((u >> 16) & 1u)) >> 16);
}

// one wave per codebook row
__global__ __launch_bounds__(256) void e2_kernel(
    const float* __restrict__ cbs, float* __restrict__ e2f)
{
    int t = blockIdx.x * 256 + threadIdx.x;    // 768 blocks -> 3072 rows
    int row = t >> 6;
    int lane = t & 63;
    float4 v = *(const float4*)(cbs + (size_t)row * D + lane * 4);
    double s = (double)v.x * v.x + (double)v.y * v.y
             + (double)v.z * v.z + (double)v.w * v.w;
    for (int o = 32; o > 0; o >>= 1) s += __shfl_down(s, o, 64);
    if (lane == 0) e2f[row] = (float)s;
}

// Pack fp32 rows into [hi(256)|lo(256)] bf16 rows (stage-0 z pack and codebooks).
__global__ __launch_bounds__(256) void pack_kernel(
    const float* __restrict__ src, unsigned short* __restrict__ dst)
{
    int t = blockIdx.x * 256 + threadIdx.x;
    int row = t >> 5;
    int k8 = (t & 31) * 8;
    size_t off = (size_t)row * D + k8;
    float4 v0 = *(const float4*)(src + off);
    float4 v1 = *(const float4*)(src + off + 4);
    float v[8] = {v0.x, v0.y, v0.z, v0.w, v1.x, v1.y, v1.z, v1.w};
    typedef __attribute__((ext_vector_type(8))) unsigned short u16x8;
    u16x8 hv, lv;
    #pragma unroll
    for (int j = 0; j < 8; ++j) {
        ushort h = f2bf(v[j]);
        hv[j] = h;
        float hf = __uint_as_float(((unsigned)h) << 16);
        lv[j] = f2bf(v[j] - hf);
    }
    *(u16x8*)(dst + (size_t)row * 512 + k8) = hv;
    *(u16x8*)(dst + (size_t)row * 512 + 256 + k8) = lv;
}

// 128 rows resident in swizzled LDS (128 KB); A windows (128 codes x 64 elems,
// 16 KB) double-buffered with counted vmcnt(4): staging of window t+1 overlaps
// compute of window t. Window order per cc: [Ahi(k4) {x Bhi,Blo}, Alo(k4) {x Bhi}]
// for k4=0..3 -> each A byte staged exactly once per block. Wave tile 4m x 4n.
__global__ __launch_bounds__(256, 1) void mfma_argmin_kernel(
    const unsigned short* __restrict__ cbp,   // [1024][512] packed bf16
    const unsigned short* __restrict__ rp,    // [32768][512] packed bf16
    const float* __restrict__ e2f,            // [1024]
    int* __restrict__ idxOut, int* __restrict__ flagcnt, int* __restrict__ flaglist)
{
    __shared__ __align__(16) __bf16 Bsm[128 * 512];   // 128 KB resident rows
    __shared__ __align__(16) __bf16 Aw[2][128 * 64];  // 2 x 16 KB A windows

    const int tid = threadIdx.x;
    const int lane = tid & 63;
    const int w = tid >> 6;
    const int wm = w >> 1, wn = w & 1;     // wm: code half of window, wn: row half
    const int hi = lane >> 4;              // 0..3
    const int lo16 = lane & 15;
    const int row0 = blockIdx.x * 128;

    // ---- prologue: stage resident B rows (linear dest, inverse-swz source) ----
    #pragma unroll
    for (int i = 0; i < 32; ++i) {
        int q = i * 256 + tid;             // 16B-chunk id, 8192 total
        int row = q >> 6;
        int c6 = q & 63;
        gload_lds16(rp + (size_t)(row0 + row) * 512 + ((c6 ^ (row & 7)) * 8),
                    (char*)Bsm + q * 16);
    }
    // stage A window 0 (cc=0, hi, k4=0) into buf 0
    #pragma unroll
    for (int r = 0; r < 4; ++r) {
        int q = r * 256 + tid;             // 1024 chunks
        int code = q >> 3;
        int lc3 = q & 7;
        gload_lds16(cbp + (size_t)code * 512 + ((lc3 ^ (code & 7)) * 8),
                    (char*)Aw[0] + q * 16);
    }
    __syncthreads();                       // full drain once (B + win0 resident)

    float d1[4], d2[4];
    int   i1[4], i2[4];
    #pragma unroll
    for (int n = 0; n < 4; ++n) {
        d1[n] = 3.4e38f; d2[n] = 3.4e38f;
        i1[n] = 0x7fffffff; i2[n] = 0x7fffffff;
    }

    for (int cc = 0; cc < 8; ++cc) {
        const unsigned short* cbBase = cbp + (size_t)cc * 65536;  // 128 codes * 512
        f32x4 acc[4][4];
        #pragma unroll
        for (int m = 0; m < 4; ++m)
            #pragma unroll
            for (int n = 0; n < 4; ++n)
                acc[m][n] = (f32x4){0.f, 0.f, 0.f, 0.f};

        #pragma unroll
        for (int j = 0; j < 8; ++j) {      // 8 windows per cc; parity = j&1
            const int k4 = j >> 1;
            const bool hiW = ((j & 1) == 0);

            // ---- stage next window into opposite parity buffer ----
            if (!(cc == 7 && j == 7)) {
                const int jn = (j + 1) & 7;
                const unsigned short* nb = (j == 7) ? (cbBase + 65536) : cbBase;
                const int aOffN = ((jn & 1) ? 256 : 0) + (jn >> 1) * 64;
                __bf16* dst = Aw[(j + 1) & 1];
                #pragma unroll
                for (int r = 0; r < 4; ++r) {
                    int q = r * 256 + tid;
                    int code = q >> 3;
                    int lc3 = q & 7;
                    gload_lds16(nb + (size_t)code * 512 + aOffN + ((lc3 ^ (code & 7)) * 8),
                                (char*)dst + q * 16);
                }
                asm volatile("s_waitcnt vmcnt(4)" ::: "memory");
            } else {
                asm volatile("s_waitcnt vmcnt(0)" ::: "memory");
            }
            __builtin_amdgcn_s_barrier();  // current window visible to all waves

            const __bf16* Ap = Aw[j & 1];
            // A fragments for this window (reused across B groups)
            bf16x8 af[2][4];
            #pragma unroll
            for (int kk = 0; kk < 2; ++kk)
                #pragma unroll
                for (int m = 0; m < 4; ++m) {
                    int cl = wm * 64 + m * 16 + lo16;
                    int lb = cl * 128 + kk * 64 + hi * 16;
                    af[kk][m] = *(const bf16x8*)((const char*)Ap + (lb ^ ((cl & 7) << 4)));
                }
            // B groups: hiW -> {Bhi(k4), Blo(k4)}; loW -> {Bhi(k4)}
            #pragma unroll
            for (int g = 0; g < 2; ++g) {
                if (g == 1 && !hiW) break;
                const int bOff = (g == 0) ? k4 * 64 : 256 + k4 * 64;
                #pragma unroll
                for (int kk = 0; kk < 2; ++kk) {
                    bf16x8 bfv[4];
                    #pragma unroll
                    for (int n = 0; n < 4; ++n) {
                        int rw = wn * 64 + n * 16 + lo16;
                        int lb = rw * 1024 + bOff * 2 + kk * 64 + hi * 16;
                        bfv[n] = *(const bf16x8*)((const char*)Bsm + (lb ^ ((rw & 7) << 4)));
                    }
                    #pragma unroll
                    for (int m = 0; m < 4; ++m)
                        #pragma unroll
                        for (int n = 0; n < 4; ++n)
                            acc[m][n] = __builtin_amdgcn_mfma_f32_16x16x32_bf16(
                                af[kk][m], bfv[n], acc[m][n], 0, 0, 0);
                }
            }
            __builtin_amdgcn_s_barrier();  // all waves done reading before overwrite
        }

        // ---- epilogue for this cc: dist = e2 - 2*dot ; update per-lane top-2 ----
        const int cb0 = cc * 128;
        float e2a[4][4];
        #pragma unroll
        for (int m = 0; m < 4; ++m) {
            float4 t = *(const float4*)(e2f + cb0 + wm * 64 + m * 16 + hi * 4);
            e2a[m][0] = t.x; e2a[m][1] = t.y; e2a[m][2] = t.z; e2a[m][3] = t.w;
        }
        #pragma unroll
        for (int n = 0; n < 4; ++n)
            #pragma unroll
            for (int m = 0; m < 4; ++m)
                #pragma unroll
                for (int r = 0; r < 4; ++r) {
                    float dv = e2a[m][r] - 2.0f * acc[m][n][r];
                    int c = cb0 + wm * 64 + m * 16 + hi * 4 + r;
                    if (dv < d1[n])      { d2[n] = d1[n]; i2[n] = i1[n]; d1[n] = dv; i1[n] = c; }
                    else if (dv < d2[n]) { d2[n] = dv; i2[n] = c; }
                }
    }

    // butterfly merge across the 4 hi-groups (same rows, different codes)
    #pragma unroll
    for (int n = 0; n < 4; ++n) {
        #pragma unroll
        for (int mk = 0; mk < 2; ++mk) {
            int mask = mk ? 32 : 16;
            float od1 = __shfl_xor(d1[n], mask, 64);
            float od2 = __shfl_xor(d2[n], mask, 64);
            int   oi1 = __shfl_xor(i1[n], mask, 64);
            int   oi2 = __shfl_xor(i2[n], mask, 64);
            if (od1 < d1[n] || (od1 == d1[n] && oi1 < i1[n])) { d2[n] = d1[n]; i2[n] = i1[n]; d1[n] = od1; i1[n] = oi1; }
            else if (od1 < d2[n] || (od1 == d2[n] && oi1 < i2[n])) { d2[n] = od1; i2[n] = oi1; }
            if (od2 < d1[n] || (od2 == d1[n] && oi2 < i1[n])) { d2[n] = d1[n]; i2[n] = i1[n]; d1[n] = od2; i1[n] = oi2; }
            else if (od2 < d2[n] || (od2 == d2[n] && oi2 < i2[n])) { d2[n] = od2; i2[n] = oi2; }
        }
    }

    // cross-wm merge via LDS scratch (A buffers are dead; last barrier passed)
    float4* mb = (float4*)Aw[0];
    if (lane < 16) {
        #pragma unroll
        for (int n = 0; n < 4; ++n)
            mb[wm * 128 + wn * 64 + n * 16 + lo16] =
                make_float4(d1[n], d2[n], __int_as_float(i1[n]), __int_as_float(i2[n]));
    }
    __syncthreads();
    if (tid < 128) {
        float4 p = mb[tid];
        float4 q = mb[128 + tid];
        float fd1 = p.x, fd2 = p.y;
        int   fi1 = __float_as_int(p.z), fi2 = __float_as_int(p.w);
        float qd1 = q.x, qd2 = q.y;
        int   qi1 = __float_as_int(q.z), qi2 = __float_as_int(q.w);
        if (qd1 < fd1 || (qd1 == fd1 && qi1 < fi1)) { fd2 = fd1; fi2 = fi1; fd1 = qd1; fi1 = qi1; }
        else if (qd1 < fd2 || (qd1 == fd2 && qi1 < fi2)) { fd2 = qd1; fi2 = qi1; }
        if (qd2 < fd1 || (qd2 == fd1 && qi2 < fi1)) { fd2 = fd1; fi2 = fi1; fd1 = qd2; fi1 = qi2; }
        else if (qd2 < fd2 || (qd2 == fd2 && qi2 < fi2)) { fd2 = qd2; fi2 = qi2; }
        int row = row0 + tid;
        idxOut[row] = fi1;
        if (fd2 - fd1 < MARGIN) {
            int pos = atomicAdd(flagcnt, 1);
            if (pos < N_ROWS) flaglist[pos] = row;
        }
    }
}

// Exact fp64 re-rank for near-tie rows. residual = z - (useQ ? qtot : 0).
__global__ __launch_bounds__(256) void refine_kernel(
    const float* __restrict__ z, const float* __restrict__ qtot,
    const float* __restrict__ cb, int* __restrict__ idxOut,
    const int* __restrict__ flagcnt, const int* __restrict__ flaglist, int useQ)
{
    __shared__ double rres[D];
    __shared__ double bd[256];
    __shared__ int    bidx[256];
    const int tid = threadIdx.x;
    int cnt = *flagcnt;
    if (cnt > N_ROWS) cnt = N_ROWS;
    for (int f = blockIdx.x; f < cnt; f += gridDim.x) {
        int row = flaglist[f];
        __syncthreads();
        {
            float zv = z[(size_t)row * D + tid];
            float qv = useQ ? qtot[(size_t)row * D + tid] : 0.0f;
            rres[tid] = (double)(zv - qv);
        }
        __syncthreads();
        double best = 1e300; int bi = 0;
        for (int j = 0; j < 4; ++j) {
            int c = tid * 4 + j;
            const float* cp = cb + (size_t)c * D;
            double s = 0.0;
            for (int k = 0; k < D; ++k) {
                double df = rres[k] - (double)cp[k];
                s = fma(df, df, s);
            }
            if (s < best) { best = s; bi = c; }
        }
        bd[tid] = best; bidx[tid] = bi;
        __syncthreads();
        for (int off = 128; off > 0; off >>= 1) {
            if (tid < off) {
                if (bd[tid + off] < bd[tid] ||
                    (bd[tid + off] == bd[tid] && bidx[tid + off] < bidx[tid])) {
                    bd[tid] = bd[tid + off]; bidx[tid] = bidx[tid + off];
                }
            }
            __syncthreads();
        }
        if (tid == 0) idxOut[row] = bidx[0];
        __syncthreads();
    }
}

// Fused: qtot += cb[idx]; residual = z - qtot; pack residual (optional);
// SSE partial per block; counts. One pass over memory.
__global__ __launch_bounds__(256) void fused_update_kernel(
    const float* __restrict__ z, float* __restrict__ qtot,
    const float* __restrict__ cb, const int* __restrict__ idxStage,
    unsigned short* __restrict__ rpOut, int* __restrict__ counts,
    double* __restrict__ ssepart, int writeRp, int firstStage)
{
    double s = 0.0;
    const int base = blockIdx.x * 256 + threadIdx.x;
    #pragma unroll
    for (int it = 0; it < 4; ++it) {
        int t = base + it * 524288;            // quad id over N_ROWS*64
        int row = t >> 6;
        int c4  = (t & 63) << 2;
        int idx = idxStage[row];
        size_t off = (size_t)row * D + c4;
        float4 cv = *(const float4*)(cb + (size_t)idx * D + c4);
        float4 qv;
        if (firstStage) {
            qv = cv;
        } else {
            qv = *(const float4*)(qtot + off);
            qv.x += cv.x; qv.y += cv.y; qv.z += cv.z; qv.w += cv.w;
        }
        *(float4*)(qtot + off) = qv;
        float4 zv = *(const float4*)(z + off);
        float r0 = zv.x - qv.x, r1 = zv.y - qv.y;
        float r2 = zv.z - qv.z, r3 = zv.w - qv.w;
        s = fma((double)r0, (double)r0, s);
        s = fma((double)r1, (double)r1, s);
        s = fma((double)r2, (double)r2, s);
        s = fma((double)r3, (double)r3, s);
        if (writeRp) {
            float rv[4] = {r0, r1, r2, r3};
            ushort4 hv, lv;
            ushort* hp = (ushort*)&hv; ushort* lp = (ushort*)&lv;
            #pragma unroll
            for (int j = 0; j < 4; ++j) {
                ushort h = f2bf(rv[j]);
                hp[j] = h;
                float hf = __uint_as_float(((unsigned)h) << 16);
                lp[j] = f2bf(rv[j] - hf);
            }
            *(ushort4*)(rpOut + (size_t)row * 512 + c4) = hv;
            *(ushort4*)(rpOut + (size_t)row * 512 + 256 + c4) = lv;
        }
        if ((t & 63) == 0) atomicAdd(counts + idx, 1);
    }
    for (int o = 32; o > 0; o >>= 1) s += __shfl_down(s, o, 64);
    __shared__ double wsum[4];
    int lane = threadIdx.x & 63, wv = threadIdx.x >> 6;
    if (lane == 0) wsum[wv] = s;
    __syncthreads();
    if (threadIdx.x == 0)
        ssepart[blockIdx.x] = wsum[0] + wsum[1] + wsum[2] + wsum[3];
}

__global__ void compose_kernel(const int* __restrict__ idxAll, float* __restrict__ comp) {
    int n = blockIdx.x * 256 + threadIdx.x;
    if (n < N_ROWS) {
        int v = idxAll[n] + (idxAll[N_ROWS + n] << 10) + (idxAll[2 * N_ROWS + n] << 20);
        comp[n] = (float)v;
    }
}

__global__ void finalize_kernel(const int* __restrict__ counts, const double* __restrict__ ssepart,
                                float* __restrict__ loss, float* __restrict__ perps)
{
    __shared__ double red[16];
    __shared__ double lossAcc;
    const int tid = threadIdx.x;   // 1024 threads
    if (tid == 0) lossAcc = 0.0;
    __syncthreads();
    for (int d = 0; d < DEPTH; ++d) {
        double p = (double)counts[d * K + tid] / 32768.0;
        double s = p * log(p + 1e-10);
        double q = ssepart[d * 2048 + tid] + ssepart[d * 2048 + 1024 + tid];
        for (int o = 32; o > 0; o >>= 1) {
            s += __shfl_down(s, o, 64);
            q += __shfl_down(q, o, 64);
        }
        if ((tid & 63) == 0) red[tid >> 6] = s;
        __syncthreads();
        if (tid == 0) {
            double tot = 0.0;
            for (int i = 0; i < 16; ++i) tot += red[i];
            perps[d] = (float)exp(-tot);
        }
        __syncthreads();
        if ((tid & 63) == 0) red[tid >> 6] = q;
        __syncthreads();
        if (tid == 0) {
            double tq = 0.0;
            for (int i = 0; i < 16; ++i) tq += red[i];
            lossAcc += tq;
        }
        __syncthreads();
    }
    if (tid == 0)
        loss[0] = (float)(1.25 * lossAcc / 8388608.0);
}

extern "C" void kernel_launch(void* const* d_in, const int* in_sizes, int n_in,
                              void* d_out, int out_size, void* d_ws, size_t ws_size,
                              hipStream_t stream)
{
    const float* z   = (const float*)d_in[0];
    const float* cbs = (const float*)d_in[1];
    float* out = (float*)d_out;
    char*  ws  = (char*)d_ws;

    int*            idxAll   = (int*)ws;
    int*            counts   = (int*)(ws + 393216);
    int*            flagcnt  = (int*)(ws + 405504);
    int*            flaglist = (int*)(ws + 405520);
    double*         ssepart  = (double*)(ws + 536592);
    float*          e2f      = (float*)(ws + 585744);
    unsigned short* cbp      = (unsigned short*)(ws + 598080);
    unsigned short* rp       = (unsigned short*)(ws + 3743808);

    float* qtot  = out;                       // 8388608 elems
    float* loss  = out + 8388608;             // 1
    float* comp  = out + 8388609;             // 32768
    float* perps = out + 8388609 + 32768;     // 3

    hipMemsetAsync(ws + 393216, 0, 405520 - 393216, stream);  // counts + flagcnt

    e2_kernel<<<768, 256, 0, stream>>>(cbs, e2f);
    pack_kernel<<<(3072 * 32) / 256, 256, 0, stream>>>(cbs, cbp);    // codebooks
    pack_kernel<<<(N_ROWS * 32) / 256, 256, 0, stream>>>(z, rp);     // stage-0 residual = z

    for (int d = 0; d < DEPTH; ++d) {
        const float* cb = cbs + (size_t)d * K * D;
        mfma_argmin_kernel<<<256, 256, 0, stream>>>(
            cbp + (size_t)d * K * 512, rp, e2f + d * K,
            idxAll + d * N_ROWS, flagcnt + d, flaglist);
        refine_kernel<<<128, 256, 0, stream>>>(
            z, qtot, cb, idxAll + d * N_ROWS, flagcnt + d, flaglist, d > 0 ? 1 : 0);
        fused_update_kernel<<<2048, 256, 0, stream>>>(
            z, qtot, cb, idxAll + d * N_ROWS, rp, counts + d * K,
            ssepart + d * 2048, d < DEPTH - 1 ? 1 : 0, d == 0 ? 1 : 0);
    }

    compose_kernel<<<(N_ROWS + 255) / 256, 256, 0, stream>>>(idxAll, comp);
    finalize_kernel<<<1, 1024, 0, stream>>>(counts, ssepart, loss, perps);
}

// Round 7
// 425.595 us; speedup vs baseline: 1.6905x; 1.2465x over previous
//
#include <hip/hip_runtime.h>
#include <math.h>

#define N_ROWS 32768
#define D 256
#define K 1024
#define DEPTH 3
#define MARGIN 0.05f

typedef __bf16 bf16x8 __attribute__((ext_vector_type(8)));
typedef float f32x4 __attribute__((ext_vector_type(4)));

// ---- ws layout (bytes) ----
// 0        idxAll[3][32768] int        -> 393216
// 393216   counts[3][1024] int         -> 405504
// 405504   flagcnt[3] int (pad to 405520)
// 405520   flaglist[32768] int         -> 536592
// 536592   ssepart[3][2048] double     -> 585744
// 585744   e2f[3][1024] float          -> 598032 (pad to 598080)
// 598080   cbp bf16 [3][1024][512]     -> 3743808
// 3743808  rp  bf16 [32768][512]       -> 37298240

__device__ __forceinline__ void gload_lds16(const void* g, void* l) {
    __builtin_amdgcn_global_load_lds(
        (const __attribute__((address_space(1))) void*)g,
        (__attribute__((address_space(3))) void*)l, 16, 0, 0);
}

__device__ __forceinline__ unsigned short f2bf(float f) {
    unsigned u = __float_as_uint(f);
    return (unsigned short)((u + 0x7fffu + ((u >> 16) & 1u)) >> 16);
}

// one wave per codebook row
__global__ __launch_bounds__(256) void e2_kernel(
    const float* __restrict__ cbs, float* __restrict__ e2f)
{
    int t = blockIdx.x * 256 + threadIdx.x;    // 768 blocks -> 3072 rows
    int row = t >> 6;
    int lane = t & 63;
    float4 v = *(const float4*)(cbs + (size_t)row * D + lane * 4);
    double s = (double)v.x * v.x + (double)v.y * v.y
             + (double)v.z * v.z + (double)v.w * v.w;
    for (int o = 32; o > 0; o >>= 1) s += __shfl_down(s, o, 64);
    if (lane == 0) e2f[row] = (float)s;
}

// Pack fp32 rows into [hi(256)|lo(256)] bf16 rows (stage-0 z pack and codebooks).
__global__ __launch_bounds__(256) void pack_kernel(
    const float* __restrict__ src, unsigned short* __restrict__ dst)
{
    int t = blockIdx.x * 256 + threadIdx.x;
    int row = t >> 5;
    int k8 = (t & 31) * 8;
    size_t off = (size_t)row * D + k8;
    float4 v0 = *(const float4*)(src + off);
    float4 v1 = *(const float4*)(src + off + 4);
    float v[8] = {v0.x, v0.y, v0.z, v0.w, v1.x, v1.y, v1.z, v1.w};
    typedef __attribute__((ext_vector_type(8))) unsigned short u16x8;
    u16x8 hv, lv;
    #pragma unroll
    for (int j = 0; j < 8; ++j) {
        ushort h = f2bf(v[j]);
        hv[j] = h;
        float hf = __uint_as_float(((unsigned)h) << 16);
        lv[j] = f2bf(v[j] - hf);
    }
    *(u16x8*)(dst + (size_t)row * 512 + k8) = hv;
    *(u16x8*)(dst + (size_t)row * 512 + 256 + k8) = lv;
}

// 8 waves (512 thr): 128 rows resident (128 KB LDS), cc = 4 chunks of 256 codes.
// A windows 256x32 elems (16 KB) double-buffered (hi->buf0, lo->buf1), counted
// vmcnt(2), 2 waves/SIMD so MFMA overlaps frag-reads + epilogue VALU of the
// sibling wave. Each cbp byte staged exactly once per block.
__global__ __launch_bounds__(512, 2) void mfma_argmin_kernel(
    const unsigned short* __restrict__ cbp,   // [1024][512] packed bf16
    const unsigned short* __restrict__ rp,    // [32768][512] packed bf16
    const float* __restrict__ e2f,            // [1024]
    int* __restrict__ idxOut, int* __restrict__ flagcnt, int* __restrict__ flaglist)
{
    __shared__ __align__(16) __bf16 Bsm[128 * 512];    // 128 KB resident rows
    __shared__ __align__(16) __bf16 Aw[2][256 * 32];   // 2 x 16 KB A windows

    const int tid = threadIdx.x;
    const int lane = tid & 63;
    const int w = tid >> 6;            // 0..7
    const int wm = w >> 1;             // code quarter of 256-chunk
    const int wn = w & 1;              // row half of 128
    const int hi = lane >> 4;          // 0..3
    const int lo16 = lane & 15;
    const int row0 = blockIdx.x * 128;

    // ---- thread-constant addressing ----
    int aPre[4], bPre[4];
    #pragma unroll
    for (int m = 0; m < 4; ++m) {
        int cl = wm * 64 + m * 16 + lo16;
        aPre[m] = cl * 64 + ((hi ^ ((cl ^ (cl >> 2)) & 3)) * 16);
    }
    #pragma unroll
    for (int n = 0; n < 4; ++n) {
        int rw = wn * 64 + n * 16 + lo16;
        bPre[n] = (rw * 1024 + hi * 16) ^ ((rw & 7) << 4);
    }
    int aSrc[2], aDst[2];
    #pragma unroll
    for (int r = 0; r < 2; ++r) {
        int q = r * 512 + tid;
        int c = q >> 2;
        int h = (q & 3) ^ ((c ^ (c >> 2)) & 3);
        aSrc[r] = c * 512 + h * 8;     // elems within cbp chunk
        aDst[r] = q * 16;              // bytes in window
    }

    // ---- prologue: stage resident B rows + first A window ----
    #pragma unroll
    for (int i = 0; i < 16; ++i) {
        int q = i * 512 + tid;
        int row = q >> 6, c6 = q & 63;
        gload_lds16(rp + (size_t)(row0 + row) * 512 + ((c6 ^ (row & 7)) * 8),
                    (char*)Bsm + q * 16);
    }
    #pragma unroll
    for (int r = 0; r < 2; ++r)
        gload_lds16(cbp + aSrc[r], (char*)Aw[0] + aDst[r]);

    float d1[4], d2[4];
    int   i1[4], i2[4];
    #pragma unroll
    for (int n = 0; n < 4; ++n) {
        d1[n] = 3.4e38f; d2[n] = 3.4e38f;
        i1[n] = 0x7fffffff; i2[n] = 0x7fffffff;
    }

    for (int cc = 0; cc < 4; ++cc) {
        const size_t cOff = (size_t)cc * 256 * 512;   // elems into cbp
        f32x4 acc[4][4];
        #pragma unroll
        for (int m = 0; m < 4; ++m)
            #pragma unroll
            for (int n = 0; n < 4; ++n)
                acc[m][n] = (f32x4){0.f, 0.f, 0.f, 0.f};

        for (int jp = 0; jp < 8; ++jp) {
            // ======== window HI(jp) in buf0 ========
            {   // stage LO(jp) -> buf1
                const int aOff = 256 + jp * 32;
                #pragma unroll
                for (int r = 0; r < 2; ++r)
                    gload_lds16(cbp + cOff + aOff + aSrc[r], (char*)Aw[1] + aDst[r]);
                asm volatile("s_waitcnt vmcnt(2)" ::: "memory");
            }
            __builtin_amdgcn_s_barrier();
            {
                bf16x8 af[4];
                #pragma unroll
                for (int m = 0; m < 4; ++m)
                    af[m] = *(const bf16x8*)((const char*)Aw[0] + aPre[m]);
                #pragma unroll
                for (int g = 0; g < 2; ++g) {          // Bhi(jp), Blo(jp)
                    const int bOffB = (g ? 512 : 0) + jp * 64;
                    bf16x8 bfv[4];
                    #pragma unroll
                    for (int n = 0; n < 4; ++n)
                        bfv[n] = *(const bf16x8*)((const char*)Bsm + (bPre[n] ^ bOffB));
                    #pragma unroll
                    for (int m = 0; m < 4; ++m)
                        #pragma unroll
                        for (int n = 0; n < 4; ++n)
                            acc[m][n] = __builtin_amdgcn_mfma_f32_16x16x32_bf16(
                                af[m], bfv[n], acc[m][n], 0, 0, 0);
                }
            }
            __builtin_amdgcn_s_barrier();
            // ======== window LO(jp) in buf1 ========
            if (!(cc == 3 && jp == 7)) {               // stage HI(next) -> buf0
                const int jn = jp + 1;
                const size_t cOffN = cOff + (size_t)(jn >> 3) * (256 * 512);
                const int aOff = (jn & 7) * 32;
                #pragma unroll
                for (int r = 0; r < 2; ++r)
                    gload_lds16(cbp + cOffN + aOff + aSrc[r], (char*)Aw[0] + aDst[r]);
                asm volatile("s_waitcnt vmcnt(2)" ::: "memory");
            } else {
                asm volatile("s_waitcnt vmcnt(0)" ::: "memory");
            }
            __builtin_amdgcn_s_barrier();
            {
                bf16x8 af[4];
                #pragma unroll
                for (int m = 0; m < 4; ++m)
                    af[m] = *(const bf16x8*)((const char*)Aw[1] + aPre[m]);
                const int bOffB = jp * 64;             // Bhi(jp) only
                bf16x8 bfv[4];
                #pragma unroll
                for (int n = 0; n < 4; ++n)
                    bfv[n] = *(const bf16x8*)((const char*)Bsm + (bPre[n] ^ bOffB));
                #pragma unroll
                for (int m = 0; m < 4; ++m)
                    #pragma unroll
                    for (int n = 0; n < 4; ++n)
                        acc[m][n] = __builtin_amdgcn_mfma_f32_16x16x32_bf16(
                            af[m], bfv[n], acc[m][n], 0, 0, 0);
            }
            __builtin_amdgcn_s_barrier();
        }

        // ---- epilogue cc: dist = e2 - 2*dot ; per-lane top-2 (codes ascending) ----
        const int cb0 = cc * 256;
        float e2a[4][4];
        #pragma unroll
        for (int m = 0; m < 4; ++m) {
            float4 t = *(const float4*)(e2f + cb0 + wm * 64 + m * 16 + hi * 4);
            e2a[m][0] = t.x; e2a[m][1] = t.y; e2a[m][2] = t.z; e2a[m][3] = t.w;
        }
        #pragma unroll
        for (int n = 0; n < 4; ++n)
            #pragma unroll
            for (int m = 0; m < 4; ++m)
                #pragma unroll
                for (int r = 0; r < 4; ++r) {
                    float dv = e2a[m][r] - 2.0f * acc[m][n][r];
                    int c = cb0 + wm * 64 + m * 16 + hi * 4 + r;
                    bool lt1 = dv < d1[n];
                    bool lt2 = dv < d2[n];
                    i2[n] = lt1 ? i1[n] : (lt2 ? c : i2[n]);
                    i1[n] = lt1 ? c : i1[n];
                    d2[n] = fminf(fmaxf(d1[n], dv), d2[n]);
                    d1[n] = fminf(d1[n], dv);
                }
    }

    // butterfly merge across the 4 hi-groups (same rows, different codes)
    #pragma unroll
    for (int n = 0; n < 4; ++n) {
        #pragma unroll
        for (int mk = 0; mk < 2; ++mk) {
            int mask = mk ? 32 : 16;
            float od1 = __shfl_xor(d1[n], mask, 64);
            float od2 = __shfl_xor(d2[n], mask, 64);
            int   oi1 = __shfl_xor(i1[n], mask, 64);
            int   oi2 = __shfl_xor(i2[n], mask, 64);
            if (od1 < d1[n] || (od1 == d1[n] && oi1 < i1[n])) { d2[n] = d1[n]; i2[n] = i1[n]; d1[n] = od1; i1[n] = oi1; }
            else if (od1 < d2[n] || (od1 == d2[n] && oi1 < i2[n])) { d2[n] = od1; i2[n] = oi1; }
            if (od2 < d1[n] || (od2 == d1[n] && oi2 < i1[n])) { d2[n] = d1[n]; i2[n] = i1[n]; d1[n] = od2; i1[n] = oi2; }
            else if (od2 < d2[n] || (od2 == d2[n] && oi2 < i2[n])) { d2[n] = od2; i2[n] = oi2; }
        }
    }

    // cross-wave merge via LDS scratch (A buffers dead after last barrier;
    // no wave touches LDS after its last trailing barrier except here)
    float4* mb = (float4*)Aw;      // 512 float4 = 8 KB scratch
    if (lane < 16) {
        #pragma unroll
        for (int n = 0; n < 4; ++n)
            mb[wm * 128 + wn * 64 + n * 16 + lo16] =
                make_float4(d1[n], d2[n], __int_as_float(i1[n]), __int_as_float(i2[n]));
    }
    __syncthreads();
    if (tid < 128) {
        float fd1 = 3.4e38f, fd2 = 3.4e38f;
        int   fi1 = 0x7fffffff, fi2 = 0x7fffffff;
        #pragma unroll
        for (int pc = 0; pc < 4; ++pc) {
            float4 p = mb[pc * 128 + tid];
            float pd1 = p.x, pd2 = p.y;
            int   pi1 = __float_as_int(p.z), pi2 = __float_as_int(p.w);
            if (pd1 < fd1 || (pd1 == fd1 && pi1 < fi1)) { fd2 = fd1; fi2 = fi1; fd1 = pd1; fi1 = pi1; }
            else if (pd1 < fd2 || (pd1 == fd2 && pi1 < fi2)) { fd2 = pd1; fi2 = pi1; }
            if (pd2 < fd1 || (pd2 == fd1 && pi2 < fi1)) { fd2 = fd1; fi2 = fi1; fd1 = pd2; fi1 = pi2; }
            else if (pd2 < fd2 || (pd2 == fd2 && pi2 < fi2)) { fd2 = pd2; fi2 = pi2; }
        }
        int row = row0 + tid;
        idxOut[row] = fi1;
        if (fd2 - fd1 < MARGIN) {
            int pos = atomicAdd(flagcnt, 1);
            if (pos < N_ROWS) flaglist[pos] = row;
        }
    }
}

// Exact fp64 re-rank for near-tie rows. residual = z - (useQ ? qtot : 0).
__global__ __launch_bounds__(256) void refine_kernel(
    const float* __restrict__ z, const float* __restrict__ qtot,
    const float* __restrict__ cb, int* __restrict__ idxOut,
    const int* __restrict__ flagcnt, const int* __restrict__ flaglist, int useQ)
{
    __shared__ double rres[D];
    __shared__ double bd[256];
    __shared__ int    bidx[256];
    const int tid = threadIdx.x;
    int cnt = *flagcnt;
    if (cnt > N_ROWS) cnt = N_ROWS;
    for (int f = blockIdx.x; f < cnt; f += gridDim.x) {
        int row = flaglist[f];
        __syncthreads();
        {
            float zv = z[(size_t)row * D + tid];
            float qv = useQ ? qtot[(size_t)row * D + tid] : 0.0f;
            rres[tid] = (double)(zv - qv);
        }
        __syncthreads();
        double best = 1e300; int bi = 0;
        for (int j = 0; j < 4; ++j) {
            int c = tid * 4 + j;
            const float* cp = cb + (size_t)c * D;
            double s = 0.0;
            for (int k = 0; k < D; ++k) {
                double df = rres[k] - (double)cp[k];
                s = fma(df, df, s);
            }
            if (s < best) { best = s; bi = c; }
        }
        bd[tid] = best; bidx[tid] = bi;
        __syncthreads();
        for (int off = 128; off > 0; off >>= 1) {
            if (tid < off) {
                if (bd[tid + off] < bd[tid] ||
                    (bd[tid + off] == bd[tid] && bidx[tid + off] < bidx[tid])) {
                    bd[tid] = bd[tid + off]; bidx[tid] = bidx[tid + off];
                }
            }
            __syncthreads();
        }
        if (tid == 0) idxOut[row] = bidx[0];
        __syncthreads();
    }
}

// Fused: qtot += cb[idx]; residual = z - qtot; pack residual (optional);
// SSE partial per block; counts. One pass over memory.
__global__ __launch_bounds__(256) void fused_update_kernel(
    const float* __restrict__ z, float* __restrict__ qtot,
    const float* __restrict__ cb, const int* __restrict__ idxStage,
    unsigned short* __restrict__ rpOut, int* __restrict__ counts,
    double* __restrict__ ssepart, int writeRp, int firstStage)
{
    double s = 0.0;
    const int base = blockIdx.x * 256 + threadIdx.x;
    #pragma unroll
    for (int it = 0; it < 4; ++it) {
        int t = base + it * 524288;            // quad id over N_ROWS*64
        int row = t >> 6;
        int c4  = (t & 63) << 2;
        int idx = idxStage[row];
        size_t off = (size_t)row * D + c4;
        float4 cv = *(const float4*)(cb + (size_t)idx * D + c4);
        float4 qv;
        if (firstStage) {
            qv = cv;
        } else {
            qv = *(const float4*)(qtot + off);
            qv.x += cv.x; qv.y += cv.y; qv.z += cv.z; qv.w += cv.w;
        }
        *(float4*)(qtot + off) = qv;
        float4 zv = *(const float4*)(z + off);
        float r0 = zv.x - qv.x, r1 = zv.y - qv.y;
        float r2 = zv.z - qv.z, r3 = zv.w - qv.w;
        s = fma((double)r0, (double)r0, s);
        s = fma((double)r1, (double)r1, s);
        s = fma((double)r2, (double)r2, s);
        s = fma((double)r3, (double)r3, s);
        if (writeRp) {
            float rv[4] = {r0, r1, r2, r3};
            ushort4 hv, lv;
            ushort* hp = (ushort*)&hv; ushort* lp = (ushort*)&lv;
            #pragma unroll
            for (int j = 0; j < 4; ++j) {
                ushort h = f2bf(rv[j]);
                hp[j] = h;
                float hf = __uint_as_float(((unsigned)h) << 16);
                lp[j] = f2bf(rv[j] - hf);
            }
            *(ushort4*)(rpOut + (size_t)row * 512 + c4) = hv;
            *(ushort4*)(rpOut + (size_t)row * 512 + 256 + c4) = lv;
        }
        if ((t & 63) == 0) atomicAdd(counts + idx, 1);
    }
    for (int o = 32; o > 0; o >>= 1) s += __shfl_down(s, o, 64);
    __shared__ double wsum[4];
    int lane = threadIdx.x & 63, wv = threadIdx.x >> 6;
    if (lane == 0) wsum[wv] = s;
    __syncthreads();
    if (threadIdx.x == 0)
        ssepart[blockIdx.x] = wsum[0] + wsum[1] + wsum[2] + wsum[3];
}

__global__ void compose_kernel(const int* __restrict__ idxAll, float* __restrict__ comp) {
    int n = blockIdx.x * 256 + threadIdx.x;
    if (n < N_ROWS) {
        int v = idxAll[n] + (idxAll[N_ROWS + n] << 10) + (idxAll[2 * N_ROWS + n] << 20);
        comp[n] = (float)v;
    }
}

__global__ void finalize_kernel(const int* __restrict__ counts, const double* __restrict__ ssepart,
                                float* __restrict__ loss, float* __restrict__ perps)
{
    __shared__ double red[16];
    __shared__ double lossAcc;
    const int tid = threadIdx.x;   // 1024 threads
    if (tid == 0) lossAcc = 0.0;
    __syncthreads();
    for (int d = 0; d < DEPTH; ++d) {
        double p = (double)counts[d * K + tid] / 32768.0;
        double s = p * log(p + 1e-10);
        double q = ssepart[d * 2048 + tid] + ssepart[d * 2048 + 1024 + tid];
        for (int o = 32; o > 0; o >>= 1) {
            s += __shfl_down(s, o, 64);
            q += __shfl_down(q, o, 64);
        }
        if ((tid & 63) == 0) red[tid >> 6] = s;
        __syncthreads();
        if (tid == 0) {
            double tot = 0.0;
            for (int i = 0; i < 16; ++i) tot += red[i];
            perps[d] = (float)exp(-tot);
        }
        __syncthreads();
        if ((tid & 63) == 0) red[tid >> 6] = q;
        __syncthreads();
        if (tid == 0) {
            double tq = 0.0;
            for (int i = 0; i < 16; ++i) tq += red[i];
            lossAcc += tq;
        }
        __syncthreads();
    }
    if (tid == 0)
        loss[0] = (float)(1.25 * lossAcc / 8388608.0);
}

extern "C" void kernel_launch(void* const* d_in, const int* in_sizes, int n_in,
                              void* d_out, int out_size, void* d_ws, size_t ws_size,
                              hipStream_t stream)
{
    const float* z   = (const float*)d_in[0];
    const float* cbs = (const float*)d_in[1];
    float* out = (float*)d_out;
    char*  ws  = (char*)d_ws;

    int*            idxAll   = (int*)ws;
    int*            counts   = (int*)(ws + 393216);
    int*            flagcnt  = (int*)(ws + 405504);
    int*            flaglist = (int*)(ws + 405520);
    double*         ssepart  = (double*)(ws + 536592);
    float*          e2f      = (float*)(ws + 585744);
    unsigned short* cbp      = (unsigned short*)(ws + 598080);
    unsigned short* rp       = (unsigned short*)(ws + 3743808);

    float* qtot  = out;                       // 8388608 elems
    float* loss  = out + 8388608;             // 1
    float* comp  = out + 8388609;             // 32768
    float* perps = out + 8388609 + 32768;     // 3

    hipMemsetAsync(ws + 393216, 0, 405520 - 393216, stream);  // counts + flagcnt

    e2_kernel<<<768, 256, 0, stream>>>(cbs, e2f);
    pack_kernel<<<(3072 * 32) / 256, 256, 0, stream>>>(cbs, cbp);    // codebooks
    pack_kernel<<<(N_ROWS * 32) / 256, 256, 0, stream>>>(z, rp);     // stage-0 residual = z

    for (int d = 0; d < DEPTH; ++d) {
        const float* cb = cbs + (size_t)d * K * D;
        mfma_argmin_kernel<<<256, 512, 0, stream>>>(
            cbp + (size_t)d * K * 512, rp, e2f + d * K,
            idxAll + d * N_ROWS, flagcnt + d, flaglist);
        refine_kernel<<<128, 256, 0, stream>>>(
            z, qtot, cb, idxAll + d * N_ROWS, flagcnt + d, flaglist, d > 0 ? 1 : 0);
        fused_update_kernel<<<2048, 256, 0, stream>>>(
            z, qtot, cb, idxAll + d * N_ROWS, rp, counts + d * K,
            ssepart + d * 2048, d < DEPTH - 1 ? 1 : 0, d == 0 ? 1 : 0);
    }

    compose_kernel<<<(N_ROWS + 255) / 256, 256, 0, stream>>>(idxAll, comp);
    finalize_kernel<<<1, 1024, 0, stream>>>(counts, ssepart, loss, perps);
}